// Round 2
// 206.055 us; speedup vs baseline: 1.0037x; 1.0037x over previous
//
#include <hip/hip_runtime.h>

// Problem constants
#define B_DIM 32
#define V_DIM 21
#define D_DIM 512
#define P_DIM 64
#define M_TOTAL 672          // B*V
#define K_TOTAL 32768        // D*P
#define OUT_DIM 96
#define E_DIM 8
#define R_DIM 8
#define H_DIM 256
#define N_TOTAL 160          // OUT_DIM + E*R
#define SCALING 2.0f
#define POOL_SCALE (1.0f / (V_DIM * (float)P_DIM))

// GEMM tiling: async global->LDS staging, double-buffered, swizzled sources.
#define BM 64
#define BK 32
#define KSPLIT 64
#define K_PER_SPLIT (K_TOTAL / KSPLIT)   // 512
#define CHUNKS (K_PER_SPLIT / BK)        // 16
#define SMN (M_TOTAL * N_TOTAL)          // 107520 per partial plane
#define RC_ROWS 2                        // rows per reduce_combine block

typedef __attribute__((ext_vector_type(4))) float floatx4;
typedef __attribute__((ext_vector_type(8))) short short8;

__device__ __forceinline__ unsigned short f2bf(float f) {
  union { float f; unsigned int u; } v; v.f = f;
  unsigned int u = v.u + (0x7FFFu + ((v.u >> 16) & 1u));  // RNE
  return (unsigned short)(u >> 16);
}

// v_cvt_pk_bf16_f32: RNE, lo -> bits[15:0], hi -> bits[31:16] (matches f2bf)
__device__ __forceinline__ unsigned int cvt_pk_bf16(float lo, float hi) {
  unsigned int r;
  asm("v_cvt_pk_bf16_f32 %0, %1, %2" : "=v"(r) : "v"(lo), "v"(hi));
  return r;
}

// async 16B global->LDS; lds ptr must be wave-uniform (HW adds lane*16)
__device__ __forceinline__ void gl_lds16(const void* g, void* l) {
  __builtin_amdgcn_global_load_lds(
      (const __attribute__((address_space(1))) void*)g,
      (__attribute__((address_space(3))) void*)l, 16, 0, 0);
}

// ------- convW: [W_base|lora_A] fp32 -> bf16 Wb[160][32768]; also zero pooled
__global__ __launch_bounds__(256)
void convW_kernel(const float* __restrict__ W_base, const float* __restrict__ lora_A,
                  short* __restrict__ Wb, float* __restrict__ pooled) {
  int gid = blockIdx.x * 256 + threadIdx.x;
  if (blockIdx.x < 64) pooled[gid] = 0.0f;   // 16384 floats zeroed (grid is 2560 blocks)
  size_t base = (size_t)gid * 8;
  int row = (int)(base >> 15);
  int k = (int)(base & 32767);
  const float* src = (row < OUT_DIM) ? (W_base + ((size_t)row << 15) + k)
                                     : (lora_A + ((size_t)(row - OUT_DIM) << 15) + k);
  floatx4 v0 = ((const floatx4*)src)[0];
  floatx4 v1 = ((const floatx4*)src)[1];
  short8 sv;
  sv[0] = (short)f2bf(v0[0]); sv[1] = (short)f2bf(v0[1]);
  sv[2] = (short)f2bf(v0[2]); sv[3] = (short)f2bf(v0[3]);
  sv[4] = (short)f2bf(v1[0]); sv[5] = (short)f2bf(v1[1]);
  sv[6] = (short)f2bf(v1[2]); sv[7] = (short)f2bf(v1[3]);
  *(short8*)(Wb + base) = sv;
}

// ------- gemm v2: async LDS-staged, double-buffered, swizzled; bf16 convert
// in-register at MFMA time; pooling from the fp32 LDS tile (swizzle-invariant).
// LDS = 2*8K (A fp32) + 2*10K (B bf16) + pool = 37 KB -> 4 blocks/CU, all
// 704 blocks co-resident. ~18 KB async in flight per block (no VGPR cost).
__global__ __launch_bounds__(256, 4)
void gemm_kernel(const float* __restrict__ x, const short* __restrict__ Wb,
                 float* __restrict__ P, float* __restrict__ pooled) {
  __shared__ __attribute__((aligned(16))) float ldsA[2][BM * BK];       // 2 x 8 KB
  __shared__ __attribute__((aligned(16))) short ldsB[2][N_TOTAL * BK];  // 2 x 10 KB
  __shared__ float lds_pool[5 * 8];       // [b_local][d_local]

  const int tid = threadIdx.x;
  const int m0 = blockIdx.x * BM;
  const int ky = blockIdx.y;
  const int kbase = ky * K_PER_SPLIT;
  const int lane = tid & 63;
  const int wave = tid >> 6;
  const int quad = lane >> 4;
  const int l16 = lane & 15;
  const int b_first = m0 / V_DIM;
  const int d_first = kbase >> 6;         // k = d*64 + p; 2 chunks == one d

  if (tid < 40) lds_pool[tid] = 0.0f;

  // ---- staging descriptors ----
  // A tile [64 rows][32 f] = 512 x 16B chunks; dest chunk idx = it*256+tid.
  // Source chunk is XOR-swizzled within the row: gchunk = j ^ (row&7), so the
  // linear LDS write leaves row r's chunk slot s holding global chunk s^(r&7).
  const float* srcA[2];
  int dstA[2];                            // wave-uniform float index into ldsA[buf]
  #pragma unroll
  for (int it = 0; it < 2; ++it) {
    int idx = it * 256 + tid;
    int row = idx >> 3, j = idx & 7;
    int m = m0 + row; if (m > M_TOTAL - 1) m = M_TOTAL - 1;   // clamp OOB rows
    srcA[it] = x + (size_t)m * K_TOTAL + kbase + ((j ^ (row & 7)) << 2);
    dstA[it] = (it * 256 + (tid & 192)) << 2;
  }
  // B tile [160 rows][32 bf16] staged as 80 row-PAIRS of 128 B (8 chunks),
  // swizzled with the pair index: dest slot s8 of pair p holds global chunk
  // c8 = s8 ^ (p&7); c8>>2 selects row-of-pair, c8&3 the 16B column.
  const short* srcB[3];
  int dstB[3];                            // wave-uniform short index into ldsB[buf]
  #pragma unroll
  for (int it = 0; it < 3; ++it) {
    int idx = it * 256 + tid;
    if (idx < 640) {
      int pair = idx >> 3, s8 = idx & 7;
      int c8 = s8 ^ (pair & 7);
      int row = pair * 2 + (c8 >> 2), j = c8 & 3;
      srcB[it] = Wb + (size_t)row * K_TOTAL + kbase + (j << 3);
      dstB[it] = (it * 256 + (tid & 192)) << 3;
    } else {
      srcB[it] = Wb; dstB[it] = 0;        // never issued (guarded below)
    }
  }

  // pooling descriptors: 4 threads per A-row, slots {(row+part)&7, +4} cover
  // all 8 chunks once (swizzle permutes within the row -> sum unaffected)
  const int prow = tid >> 2;
  const int part = tid & 3;
  const int ps1 = (prow + part) & 7;
  const int ps2 = (ps1 + 4) & 7;
  const int pm = m0 + prow;
  const int pool_base = (pm < M_TOTAL) ? ((pm / V_DIM) - b_first) * 8 : -1;

#define ISSUE(c, bb)                                                          \
  {                                                                           \
    _Pragma("unroll")                                                         \
    for (int it = 0; it < 2; ++it)                                            \
      gl_lds16(srcA[it] + (c) * BK, &ldsA[bb][dstA[it]]);                     \
    _Pragma("unroll")                                                         \
    for (int it = 0; it < 2; ++it)                                            \
      gl_lds16(srcB[it] + (c) * BK, &ldsB[bb][dstB[it]]);                     \
    if (tid < 128) gl_lds16(srcB[2] + (c) * BK, &ldsB[bb][dstB[2]]);          \
  }

  floatx4 acc[10];                        // wave: rows [wave*16,+16), all 160 n
  #pragma unroll
  for (int nt = 0; nt < 10; ++nt) acc[nt] = (floatx4)(0.0f);

  ISSUE(0, 0);
  __syncthreads();            // drains chunk-0 loads; lds_pool zeros visible

  #pragma unroll
  for (int c = 0; c < CHUNKS; ++c) {
    const int buf = c & 1;
    if (c + 1 < CHUNKS) ISSUE(c + 1, buf ^ 1);   // ~18 KB async under compute
    // pooling over this chunk's fp32 A tile
    {
      const floatx4* aT = (const floatx4*)ldsA[buf];
      floatx4 u = aT[prow * 8 + ps1];
      floatx4 w = aT[prow * 8 + ps2];
      float s = ((u[0] + u[1]) + (u[2] + u[3])) + ((w[0] + w[1]) + (w[2] + w[3]));
      s += __shfl_down(s, 2, 4);
      s += __shfl_down(s, 1, 4);
      if (part == 0 && pool_base >= 0)
        atomicAdd(&lds_pool[pool_base + (c >> 1)], s);
    }
    // MFMA: A fragment = floats [quad*8, +8) of row r, read via swizzled slots,
    // converted to bf16 in-register (reused across all 10 B tiles)
    {
      const floatx4* aT = (const floatx4*)ldsA[buf];
      const int r = wave * 16 + l16;
      floatx4 f0 = aT[r * 8 + ((2 * quad) ^ (r & 7))];
      floatx4 f1 = aT[r * 8 + ((2 * quad + 1) ^ (r & 7))];
      union { short8 s; unsigned int u[4]; } av;
      av.u[0] = cvt_pk_bf16(f0[0], f0[1]);
      av.u[1] = cvt_pk_bf16(f0[2], f0[3]);
      av.u[2] = cvt_pk_bf16(f1[0], f1[1]);
      av.u[3] = cvt_pk_bf16(f1[2], f1[3]);
      const short8* bT = (const short8*)ldsB[buf];
      #pragma unroll
      for (int nt = 0; nt < 10; ++nt) {
        int r2 = nt * 16 + l16;
        int pr = r2 >> 1;
        short8 b = bT[pr * 8 + ((((r2 & 1) << 2) | quad) ^ (pr & 7))];
        acc[nt] = __builtin_amdgcn_mfma_f32_16x16x32_bf16(av.s, b, acc[nt], 0, 0, 0);
      }
    }
    __syncthreads();          // drains c+1 async loads + all LDS reads of c
  }

  // partial-plane store (D layout: col=lane&15, row=quad*4+reg) — plain stores
  {
    const int mrow = m0 + wave * 16 + quad * 4;
    float* Pp = P + (size_t)ky * SMN + (size_t)mrow * N_TOTAL + l16;
    #pragma unroll
    for (int r = 0; r < 4; ++r)
      if (mrow + r < M_TOTAL)
        #pragma unroll
        for (int nt = 0; nt < 10; ++nt)
          Pp[(size_t)r * N_TOTAL + nt * 16] = acc[nt][r];
  }

  // pooled partials -> global (40 atomics/block); all lds_pool atomics are
  // before the final loop barrier, so visible here
  if (tid < 40) {
    int b = b_first + (tid >> 3);
    int d = d_first + (tid & 7);
    if (b < B_DIM)
      atomicAdd(&pooled[b * D_DIM + d], lds_pool[tid] * POOL_SCALE);
  }
}

// ---------------- router: MLP + softmax + top-2 ------------------------------
__global__ __launch_bounds__(256)
void router_kernel(const float* __restrict__ pooled, const float* __restrict__ W1,
                   const float* __restrict__ b1, const float* __restrict__ W2,
                   const float* __restrict__ b2, float* __restrict__ wfull,
                   float* __restrict__ probs_out) {
  __shared__ float sp[D_DIM];
  __shared__ float sh[H_DIM];
  __shared__ float slog[E_DIM];
  const int b = blockIdx.x;
  const int t = threadIdx.x;
  sp[t] = pooled[b * D_DIM + t];
  sp[t + 256] = pooled[b * D_DIM + t + 256];
  __syncthreads();
  float acc = b1[t];
  const float* w1r = W1 + (size_t)t * D_DIM;
  for (int d = 0; d < D_DIM; ++d) acc += sp[d] * w1r[d];
  sh[t] = fmaxf(acc, 0.0f);
  __syncthreads();
  if (t < E_DIM) {
    float a = b2[t];
    const float* w2r = W2 + t * H_DIM;
    for (int j = 0; j < H_DIM; ++j) a += sh[j] * w2r[j];
    slog[t] = a;
  }
  __syncthreads();
  if (t == 0) {
    float p[E_DIM];
    float mx = slog[0];
    for (int e = 1; e < E_DIM; ++e) mx = fmaxf(mx, slog[e]);
    float se = 0.0f;
    for (int e = 0; e < E_DIM; ++e) { p[e] = __expf(slog[e] - mx); se += p[e]; }
    float inv = 1.0f / se;
    for (int e = 0; e < E_DIM; ++e) { p[e] *= inv; probs_out[b * E_DIM + e] = p[e]; }
    // top-2, lowest index wins ties (strict > keeps earlier index)
    int i0 = 0;
    for (int e = 1; e < E_DIM; ++e) if (p[e] > p[i0]) i0 = e;
    int i1 = (i0 == 0) ? 1 : 0;
    for (int e = 0; e < E_DIM; ++e) if (e != i0 && p[e] > p[i1]) i1 = e;
    float s2 = p[i0] + p[i1];
    float invs = 1.0f / fmaxf(s2, 1e-6f);
    for (int e = 0; e < E_DIM; ++e) {
      float w = 0.0f;
      if (e == i0) w += p[i0] * invs;
      if (e == i1) w += p[i1] * invs;
      wfull[b * E_DIM + e] = w;
    }
  }
}

// ------- reduce partials over KSPLIT + combine: out = S_b + b_base + 2*Σ w·(S_l·B)
__global__ __launch_bounds__(256)
void reduce_combine_kernel(const float* __restrict__ P, const float* __restrict__ b_base,
                           const float* __restrict__ lora_B, const float* __restrict__ wfull,
                           float* __restrict__ out) {
  __shared__ float sS[RC_ROWS * N_TOTAL];   // 320 floats
  const int t = threadIdx.x;
  const size_t base = (size_t)blockIdx.x * (RC_ROWS * N_TOTAL);
  for (int s = t; s < RC_ROWS * N_TOTAL; s += 256) {
    const float* Pp = P + base + s;
    float a = 0.0f;
    #pragma unroll 8
    for (int k = 0; k < KSPLIT; ++k) a += Pp[(size_t)k * SMN];
    sS[s] = a;
  }
  __syncthreads();
  if (t < RC_ROWS * OUT_DIM) {
    int mr = t / OUT_DIM;
    int o = t - mr * OUT_DIM;
    int mm = blockIdx.x * RC_ROWS + mr;
    int b = mm / V_DIM;
    const float* srow = sS + mr * N_TOTAL;
    float res = srow[o] + b_base[o];
    float moe = 0.0f;
    #pragma unroll
    for (int e = 0; e < E_DIM; ++e) {
      float we = wfull[b * E_DIM + e];
      if (we != 0.0f) {
        const float* lb = lora_B + ((size_t)e * OUT_DIM + o) * R_DIM;
        float dd = 0.0f;
        #pragma unroll
        for (int r = 0; r < R_DIM; ++r) dd += srow[OUT_DIM + e * R_DIM + r] * lb[r];
        moe += we * dd;
      }
    }
    out[(size_t)mm * OUT_DIM + o] = res + SCALING * moe;
  }
}

extern "C" void kernel_launch(void* const* d_in, const int* in_sizes, int n_in,
                              void* d_out, int out_size, void* d_ws, size_t ws_size,
                              hipStream_t stream) {
  const float* x      = (const float*)d_in[0];
  const float* W_base = (const float*)d_in[1];
  const float* b_base = (const float*)d_in[2];
  const float* W1     = (const float*)d_in[3];
  const float* b1     = (const float*)d_in[4];
  const float* W2     = (const float*)d_in[5];
  const float* b2     = (const float*)d_in[6];
  const float* lora_A = (const float*)d_in[7];
  const float* lora_B = (const float*)d_in[8];
  float* out = (float*)d_out;

  // ws layout: pooled[16384 f] | wfull[256 f] | Wb[160*32768 bf16] | P[64*107520 f]
  float* ws     = (float*)d_ws;
  float* pooled = ws;
  float* wfull  = ws + 16384;
  short* Wb     = (short*)(wfull + 256);
  float* P      = (float*)(Wb + (size_t)N_TOTAL * K_TOTAL);

  convW_kernel<<<(N_TOTAL * K_TOTAL / 8 + 255) / 256, 256, 0, stream>>>(
      W_base, lora_A, Wb, pooled);
  gemm_kernel<<<dim3(11, KSPLIT), 256, 0, stream>>>(x, Wb, P, pooled);
  router_kernel<<<B_DIM, 256, 0, stream>>>(pooled, W1, b1, W2, b2, wfull,
                                           out + (size_t)M_TOTAL * OUT_DIM);
  reduce_combine_kernel<<<M_TOTAL / RC_ROWS, 256, 0, stream>>>(
      P, b_base, lora_B, wfull, out);
}